// Round 15
// baseline (773.620 us; speedup 1.0000x reference)
//
#include <hip/hip_runtime.h>
#include <cmath>

#define D 64
#define HD 128
#define K1 192
#define TT 8192
#define BBATCH 32
#define RULES 4

typedef _Float16 f16x8 __attribute__((ext_vector_type(8)));
typedef _Float16 f16x4 __attribute__((ext_vector_type(4)));
typedef float f32x4 __attribute__((ext_vector_type(4)));

__device__ __forceinline__ float gelu_exact(float x) {
    return 0.5f * x * (1.0f + erff(x * 0.70710678118654752f));
}

__device__ __forceinline__ float fast_rcp(float x) { return __builtin_amdgcn_rcpf(x); }
__device__ __forceinline__ float fast_exp2(float x) { return __builtin_amdgcn_exp2f(x); }

// tanh-approx GELU (R8, passing): ~6 VALU + 2 trans.
__device__ __forceinline__ float gelu_tanh(float x) {
    float x2 = x * x;
    float t = x * fmaf(x2, -0.10294443f, -2.30220820f);
    return x * fast_rcp(1.0f + fast_exp2(t));
}
// tanh(x) = 1 - 2/(exp2(2*log2e*x)+1) ; exact identity, saturates cleanly
__device__ __forceinline__ float fast_tanh(float x) {
    float e = fast_exp2(x * 2.8853900817779268f);
    return 1.0f - 2.0f * fast_rcp(e + 1.0f);
}

__device__ __forceinline__ f16x4 cvt4_rne(float a, float b, float c, float d) {
    f16x4 r;
    r[0] = (_Float16)a; r[1] = (_Float16)b;
    r[2] = (_Float16)c; r[3] = (_Float16)d;
    return r;
}

// ---------------------------------------------------------------------------
// Prep+control kernel (unchanged from R14 — verified):
//   blocks 0..63: weight re-layout; block 64: control -> ctrl[0..5].
// ---------------------------------------------------------------------------
__global__ __launch_bounds__(256) void prep_control_kernel(
    const float* __restrict__ rule_w1, const float* __restrict__ rule_w2,
    _Float16* __restrict__ w1b, _Float16* __restrict__ w2b,
    const float* __restrict__ c_state,
    const float* __restrict__ sel_w1, const float* __restrict__ sel_b1,
    const float* __restrict__ sel_w2, const float* __restrict__ sel_b2,
    const float* __restrict__ st_w1,  const float* __restrict__ st_b1,
    const float* __restrict__ st_w2,  const float* __restrict__ st_b2,
    const float* __restrict__ res_w1, const float* __restrict__ res_b1,
    const float* __restrict__ res_w2, const float* __restrict__ res_b2,
    float* __restrict__ ctrl)
{
    if (blockIdx.x < 64) {
        int t = blockIdx.x * 256 + threadIdx.x;
        if (t < 12288) {
            int lane = t & 63;
            int x = t >> 6;          // 0..191
            int htile = x & 31;      // global h tile (r = htile>>3)
            int ks = x >> 5;         // 0..5
            int r = htile >> 3;
            int h128 = (htile & 7) * 16 + (lane & 15);
            int kbase = ks * 32 + (lane >> 4) * 8;
            f16x8 v;
#pragma unroll
            for (int j = 0; j < 8; ++j)
                v[j] = (_Float16)rule_w1[((size_t)r * K1 + kbase + j) * HD + h128];
            ((f16x8*)w1b)[(ks * 32 + htile) * 64 + lane] = v;
        } else if (t < 12288 + 4096) {
            int u = t - 12288;
            int lane = u & 63;
            int mt = (u >> 6) & 3;   // d tile
            int ks2 = (u >> 8) & 3;  // hidden-k tile
            int r = u >> 10;
            int kbase = ks2 * 32 + (lane >> 4) * 8;
            int d = mt * 16 + (lane & 15);
            f16x8 v;
#pragma unroll
            for (int j = 0; j < 8; ++j)
                v[j] = (_Float16)rule_w2[((size_t)r * HD + kbase + j) * D + d];
            ((f16x8*)w2b)[((r * 4 + ks2) * 4 + mt) * 64 + lane] = v;
        }
        return;
    }

    // ---- control block (blockIdx.x == 64)
    __shared__ float cs[128];
    __shared__ float h1s[64], h2s[32], h3s[32];
    __shared__ float lg[12];
    int l = threadIdx.x;
    if (l < 64) { cs[l] = c_state[l]; cs[l + 64] = c_state[l + 64]; }
    __syncthreads();
    if (l < 64) {
        float a = sel_b1[l];
        for (int k = 0; k < 128; ++k) a += cs[k] * sel_w1[k * 64 + l];
        h1s[l] = gelu_exact(a);
    }
    if (l < 32) {
        float a = st_b1[l];
        for (int k = 0; k < 128; ++k) a += cs[k] * st_w1[k * 32 + l];
        h2s[l] = gelu_exact(a);
        float a2 = res_b1[l];
        for (int k = 0; k < 128; ++k) a2 += cs[k] * res_w1[k * 32 + l];
        h3s[l] = gelu_exact(a2);
    }
    __syncthreads();
    if (l < 4) {
        float a = sel_b2[l];
        for (int j = 0; j < 64; ++j) a += h1s[j] * sel_w2[j * 4 + l];
        lg[l] = a;
    }
    if (l >= 8 && l < 15) {
        int s = l - 8;
        float a = st_b2[s];
        for (int j = 0; j < 32; ++j) a += h2s[j] * st_w2[j * 7 + s];
        lg[4 + s] = a;
    }
    if (l == 32) {
        float a = res_b2[0];
        for (int j = 0; j < 32; ++j) a += h3s[j] * res_w2[j];
        lg[11] = a;
    }
    __syncthreads();
    if (l == 0) {
        float m = fmaxf(fmaxf(lg[0], lg[1]), fmaxf(lg[2], lg[3]));
        float e0 = expf(lg[0] - m), e1 = expf(lg[1] - m);
        float e2 = expf(lg[2] - m), e3 = expf(lg[3] - m);
        float s = e0 + e1 + e2 + e3;
        ctrl[0] = e0 / s; ctrl[1] = e1 / s; ctrl[2] = e2 / s; ctrl[3] = e3 / s;
        float m2 = lg[4];
        for (int i = 1; i < 7; ++i) m2 = fmaxf(m2, lg[4 + i]);
        float ss = 0.f, es[7];
        for (int i = 0; i < 7; ++i) { es[i] = expf(lg[4 + i] - m2); ss += es[i]; }
        float nsoft = 0.f;
        for (int i = 0; i < 7; ++i) nsoft += (es[i] / ss) * (float)(i + 2);
        int n = (int)(nsoft + 0.5f);
        n = n < 2 ? 2 : (n > 8 ? 8 : n);
        float alpha = 0.1f + 0.8f / (1.0f + expf(-lg[11]));
        ctrl[4] = alpha;
        ctrl[5] = (float)n;
    }
}

// ---------------------------------------------------------------------------
// Evolve kernel R15: 64-token tile, 512 threads = 8 waves.
// Wave w: rule r = w>>1, token-half th = w&1 (32 tokens).
// Same math/LDS layout as R8/R14; GEMM1->GEMM2 chain stays wave-private
// (each wave computes and consumes H only for its own 32 tokens; the f32
// mix-write overwrites only its own H half). 2 barriers as before.
// LDS 79 KB -> 2 blocks/CU x 8 waves = 4 waves/SIMD (2x R14 occupancy).
// Buffers device-selected with backwards parity (verified R10/R14): the
// last iteration's src is always bufA, so fused-LN write to `out` is safe.
// ---------------------------------------------------------------------------
__global__ __launch_bounds__(512, 4) void evolve_kernel(
    const float* __restrict__ cells, float* __restrict__ bufA,
    float* __restrict__ out, const float* __restrict__ ctrl,
    const _Float16* __restrict__ w1b, const _Float16* __restrict__ w2b,
    const float* __restrict__ b1, const float* __restrict__ b2,
    const float* __restrict__ ln_g, const float* __restrict__ ln_b, int iter)
{
    int n = (int)ctrl[5];
    if (iter >= n) return;
    const bool last = (iter == n - 1);

    const float* src = (iter == 0) ? cells
                       : ((((n - 1 - iter) & 1) == 0) ? (const float*)bufA
                                                      : (const float*)out);
    float* dst = (((n - 2 - iter) & 1) == 0) ? bufA : out;  // unused if last

    float alpha = ctrl[4];
    float beta = 1.0f - alpha;

    __shared__ _Float16 cellsL[66 * 72];                     // 9504 B
    __shared__ __align__(16) _Float16 arena[4][64 * 136];    // 4 x 17408 B

    int tile = blockIdx.x;
    int b = tile >> 7;
    int t0 = (tile & 127) << 6;
    const float* srcb = src + (size_t)b * TT * D;

    int tid = threadIdx.x;
    // stage cells tile (fp32 -> f16 LDS, RNE casts); 512 threads
    for (int idx = tid; idx < 66 * 16; idx += 512) {
        int row = idx >> 4;
        int c4 = (idx & 15) << 2;
        int tok = (t0 - 1 + row) & (TT - 1);
        f32x4 v = *(const f32x4*)(srcb + (size_t)tok * D + c4);
        *(f16x4*)&cellsL[row * 72 + c4] = cvt4_rne(v[0], v[1], v[2], v[3]);
    }
    __syncthreads();   // barrier 1

    int wave = tid >> 6;       // 0..7
    int lane = tid & 63;
    int lrow = lane & 15;
    int lgrp = lane >> 4;
    int r  = wave >> 1;        // rule
    int th = wave & 1;         // token half (32 tokens)
    float rwr = ctrl[r];

    const f16x8* w1v = (const f16x8*)w1b;
    const f16x8* w2v = (const f16x8*)w2b;
    _Float16* hb = &arena[r][0];

    // ---- GEMM1: h^T = W1_r^T X^T  (128 hcols x this wave's 32 tokens)
    f32x4 acc1[8][2];
#pragma unroll
    for (int ht = 0; ht < 8; ++ht)
#pragma unroll
        for (int nt = 0; nt < 2; ++nt)
            acc1[ht][nt] = (f32x4){0.f, 0.f, 0.f, 0.f};

#pragma unroll
    for (int ks = 0; ks < 6; ++ks) {
        int k0 = ks * 32 + lgrp * 8;
        int seg = k0 >> 6;                     // 0:c[t] 1:c[t-1] 2:c[t+1]
        int kk = k0 & 63;
        int drow = (seg == 0) ? 1 : ((seg == 1) ? 0 : 2);
        f16x8 a_[2];
#pragma unroll
        for (int nt = 0; nt < 2; ++nt)
            a_[nt] = *(const f16x8*)
                &cellsL[(th * 32 + nt * 16 + lrow + drow) * 72 + kk];
#pragma unroll
        for (int ht = 0; ht < 8; ++ht) {
            f16x8 wf = w1v[(ks * 32 + r * 8 + ht) * 64 + lane];
#pragma unroll
            for (int nt = 0; nt < 2; ++nt)
                acc1[ht][nt] = __builtin_amdgcn_mfma_f32_16x16x32_f16(wf, a_[nt], acc1[ht][nt], 0, 0, 0);
        }
    }

    // gelu + H store (wave-private rows: th*32 .. th*32+32)
#pragma unroll
    for (int ht = 0; ht < 8; ++ht) {
        f32x4 b1v = *(const f32x4*)&b1[r * HD + ht * 16 + lgrp * 4];
#pragma unroll
        for (int nt = 0; nt < 2; ++nt) {
            float g0 = gelu_tanh(acc1[ht][nt][0] + b1v[0]);
            float g1 = gelu_tanh(acc1[ht][nt][1] + b1v[1]);
            float g2 = gelu_tanh(acc1[ht][nt][2] + b1v[2]);
            float g3 = gelu_tanh(acc1[ht][nt][3] + b1v[3]);
            *(f16x4*)&hb[(th * 32 + nt * 16 + lrow) * 136 + ht * 16 + lgrp * 4]
                = cvt4_rne(g0, g1, g2, g3);
        }
    }

    // ---- GEMM2: out^T = W2_r^T H^T (64 d x own 32 tokens), wave-private
    f32x4 acc2[4][2];
#pragma unroll
    for (int mt = 0; mt < 4; ++mt)
#pragma unroll
        for (int nt = 0; nt < 2; ++nt)
            acc2[mt][nt] = (f32x4){0.f, 0.f, 0.f, 0.f};

#pragma unroll
    for (int ks2 = 0; ks2 < 4; ++ks2) {
        f16x8 a2[2];
#pragma unroll
        for (int nt = 0; nt < 2; ++nt)
            a2[nt] = *(const f16x8*)
                &hb[(th * 32 + nt * 16 + lrow) * 136 + ks2 * 32 + lgrp * 8];
#pragma unroll
        for (int mt = 0; mt < 4; ++mt) {
            f16x8 bw = w2v[((r * 4 + ks2) * 4 + mt) * 64 + lane];
#pragma unroll
            for (int nt = 0; nt < 2; ++nt)
                acc2[mt][nt] = __builtin_amdgcn_mfma_f32_16x16x32_f16(bw, a2[nt], acc2[mt][nt], 0, 0, 0);
        }
    }

    // tanh * rule_weight -> f32 mix slice over OWN half (H dead for this
    // wave after its GEMM2 reads; partner wave touches only its own half)
    float* mixw = (float*)hb;   // [64 tokens][stride 68 f32]
#pragma unroll
    for (int mt = 0; mt < 4; ++mt) {
        f32x4 b2v = *(const f32x4*)&b2[r * D + mt * 16 + lgrp * 4];
#pragma unroll
        for (int nt = 0; nt < 2; ++nt) {
            f32x4 o;
#pragma unroll
            for (int q = 0; q < 4; ++q)
                o[q] = rwr * fast_tanh(acc2[mt][nt][q] + b2v[q]);
            *(f32x4*)&mixw[(th * 32 + nt * 16 + lrow) * 68 + mt * 16 + lgrp * 4] = o;
        }
    }

    __syncthreads();   // barrier 2

    // ---- cross-rule reduce + alpha mix; thread -> (token, d-eighth)
    int tok = tid >> 3;                 // 0..63
    int dq = tid & 7;                   // 8 contiguous d per thread
    const float* ar0 = (const float*)&arena[0][0];
    const float* ar1 = (const float*)&arena[1][0];
    const float* ar2 = (const float*)&arena[2][0];
    const float* ar3 = (const float*)&arena[3][0];
    int mbase = tok * 68 + dq * 8;
    size_t roff = (size_t)b * TT * D + (size_t)(t0 + tok) * D + dq * 8;

    f32x4 ov[2];
    float m0 = 0.f, m1 = 0.f;
#pragma unroll
    for (int j = 0; j < 2; ++j) {
        f32x4 v0 = *(const f32x4*)(ar0 + mbase + j * 4);
        f32x4 v1 = *(const f32x4*)(ar1 + mbase + j * 4);
        f32x4 v2 = *(const f32x4*)(ar2 + mbase + j * 4);
        f32x4 v3 = *(const f32x4*)(ar3 + mbase + j * 4);
        f32x4 s  = *(const f32x4*)(src + roff + j * 4);
#pragma unroll
        for (int q = 0; q < 4; ++q) {
            float v = alpha * s[q] + beta * (v0[q] + v1[q] + v2[q] + v3[q]);
            ov[j][q] = v; m0 += v; m1 += v * v;
        }
    }

    if (!last) {
#pragma unroll
        for (int j = 0; j < 2; ++j)
            *(f32x4*)(dst + roff + j * 4) = ov[j];
    } else {
        // fused LayerNorm: token's 64 d live in 8 consecutive lanes
        m0 += __shfl_xor(m0, 1, 64); m1 += __shfl_xor(m1, 1, 64);
        m0 += __shfl_xor(m0, 2, 64); m1 += __shfl_xor(m1, 2, 64);
        m0 += __shfl_xor(m0, 4, 64); m1 += __shfl_xor(m1, 4, 64);
        float mu = m0 * (1.0f / 64.0f);
        float inv = rsqrtf(m1 * (1.0f / 64.0f) - mu * mu + 1e-5f);
#pragma unroll
        for (int j = 0; j < 2; ++j) {
            f32x4 g4 = *(const f32x4*)&ln_g[dq * 8 + j * 4];
            f32x4 b4 = *(const f32x4*)&ln_b[dq * 8 + j * 4];
            f32x4 o;
#pragma unroll
            for (int q = 0; q < 4; ++q)
                o[q] = (ov[j][q] - mu) * inv * g4[q] + b4[q];
            *(f32x4*)(out + roff + j * 4) = o;
        }
    }
}

// ---------------------------------------------------------------------------
extern "C" void kernel_launch(void* const* d_in, const int* in_sizes, int n_in,
                              void* d_out, int out_size, void* d_ws, size_t ws_size,
                              hipStream_t stream) {
    const float* cells   = (const float*)d_in[0];
    const float* c_state = (const float*)d_in[1];
    const float* rule_w1 = (const float*)d_in[2];
    const float* rule_b1 = (const float*)d_in[3];
    const float* rule_w2 = (const float*)d_in[4];
    const float* rule_b2 = (const float*)d_in[5];
    const float* sel_w1  = (const float*)d_in[6];
    const float* sel_b1  = (const float*)d_in[7];
    const float* sel_w2  = (const float*)d_in[8];
    const float* sel_b2  = (const float*)d_in[9];
    const float* st_w1   = (const float*)d_in[10];
    const float* st_b1   = (const float*)d_in[11];
    const float* st_w2   = (const float*)d_in[12];
    const float* st_b2   = (const float*)d_in[13];
    const float* res_w1  = (const float*)d_in[14];
    const float* res_b1  = (const float*)d_in[15];
    const float* res_w2  = (const float*)d_in[16];
    const float* res_b2  = (const float*)d_in[17];
    const float* ln_g    = (const float*)d_in[18];
    const float* ln_b    = (const float*)d_in[19];

    float* out = (float*)d_out;
    char* ws = (char*)d_ws;
    float* ctrl = (float*)ws;                              // 64 B
    _Float16* w1b = (_Float16*)(ws + 256);                 // 196608 B
    _Float16* w2b = (_Float16*)(ws + 256 + 196608);        // 65536 B
    float* bufA = (float*)(ws + (512u * 1024u));           // 64 MiB ping buffer

    prep_control_kernel<<<65, 256, 0, stream>>>(
        rule_w1, rule_w2, w1b, w2b, c_state,
        sel_w1, sel_b1, sel_w2, sel_b2,
        st_w1, st_b1, st_w2, st_b2,
        res_w1, res_b1, res_w2, res_b2, ctrl);

    // 8 potential iterations; dead ones early-exit on device. Buffers are
    // selected on-device (backwards parity); last live iteration applies
    // fused LayerNorm and writes d_out.
    for (int i = 0; i < 8; ++i) {
        evolve_kernel<<<4096, 512, 0, stream>>>(cells, bufA, out, ctrl,
                                                w1b, w2b, rule_b1, rule_b2,
                                                ln_g, ln_b, i);
    }
}

// Round 16
// 607.144 us; speedup vs baseline: 1.2742x; 1.2742x over previous
//
#include <hip/hip_runtime.h>
#include <cmath>

#define D 64
#define HD 128
#define K1 192
#define TT 8192
#define BBATCH 32
#define RULES 4

typedef _Float16 f16x8 __attribute__((ext_vector_type(8)));
typedef _Float16 f16x4 __attribute__((ext_vector_type(4)));
typedef float f32x4 __attribute__((ext_vector_type(4)));

__device__ __forceinline__ float gelu_exact(float x) {
    return 0.5f * x * (1.0f + erff(x * 0.70710678118654752f));
}

__device__ __forceinline__ float fast_rcp(float x) { return __builtin_amdgcn_rcpf(x); }
__device__ __forceinline__ float fast_exp2(float x) { return __builtin_amdgcn_exp2f(x); }

// tanh-approx GELU (R8, passing): ~6 VALU + 2 trans.
__device__ __forceinline__ float gelu_tanh(float x) {
    float x2 = x * x;
    float t = x * fmaf(x2, -0.10294443f, -2.30220820f);
    return x * fast_rcp(1.0f + fast_exp2(t));
}
// tanh(x) = 1 - 2/(exp2(2*log2e*x)+1) ; exact identity, saturates cleanly
__device__ __forceinline__ float fast_tanh(float x) {
    float e = fast_exp2(x * 2.8853900817779268f);
    return 1.0f - 2.0f * fast_rcp(e + 1.0f);
}

__device__ __forceinline__ f16x4 cvt4_rne(float a, float b, float c, float d) {
    f16x4 r;
    r[0] = (_Float16)a; r[1] = (_Float16)b;
    r[2] = (_Float16)c; r[3] = (_Float16)d;
    return r;
}

// ---------------------------------------------------------------------------
// Prep+control kernel (unchanged from R14 — verified):
//   blocks 0..63: weight re-layout; block 64: control -> ctrl[0..5].
// ---------------------------------------------------------------------------
__global__ __launch_bounds__(256) void prep_control_kernel(
    const float* __restrict__ rule_w1, const float* __restrict__ rule_w2,
    _Float16* __restrict__ w1b, _Float16* __restrict__ w2b,
    const float* __restrict__ c_state,
    const float* __restrict__ sel_w1, const float* __restrict__ sel_b1,
    const float* __restrict__ sel_w2, const float* __restrict__ sel_b2,
    const float* __restrict__ st_w1,  const float* __restrict__ st_b1,
    const float* __restrict__ st_w2,  const float* __restrict__ st_b2,
    const float* __restrict__ res_w1, const float* __restrict__ res_b1,
    const float* __restrict__ res_w2, const float* __restrict__ res_b2,
    float* __restrict__ ctrl)
{
    if (blockIdx.x < 64) {
        int t = blockIdx.x * 256 + threadIdx.x;
        if (t < 12288) {
            int lane = t & 63;
            int x = t >> 6;          // 0..191
            int htile = x & 31;      // global h tile (r = htile>>3)
            int ks = x >> 5;         // 0..5
            int r = htile >> 3;
            int h128 = (htile & 7) * 16 + (lane & 15);
            int kbase = ks * 32 + (lane >> 4) * 8;
            f16x8 v;
#pragma unroll
            for (int j = 0; j < 8; ++j)
                v[j] = (_Float16)rule_w1[((size_t)r * K1 + kbase + j) * HD + h128];
            ((f16x8*)w1b)[(ks * 32 + htile) * 64 + lane] = v;
        } else if (t < 12288 + 4096) {
            int u = t - 12288;
            int lane = u & 63;
            int mt = (u >> 6) & 3;   // d tile
            int ks2 = (u >> 8) & 3;  // hidden-k tile
            int r = u >> 10;
            int kbase = ks2 * 32 + (lane >> 4) * 8;
            int d = mt * 16 + (lane & 15);
            f16x8 v;
#pragma unroll
            for (int j = 0; j < 8; ++j)
                v[j] = (_Float16)rule_w2[((size_t)r * HD + kbase + j) * D + d];
            ((f16x8*)w2b)[((r * 4 + ks2) * 4 + mt) * 64 + lane] = v;
        }
        return;
    }

    // ---- control block (blockIdx.x == 64)
    __shared__ float cs[128];
    __shared__ float h1s[64], h2s[32], h3s[32];
    __shared__ float lg[12];
    int l = threadIdx.x;
    if (l < 64) { cs[l] = c_state[l]; cs[l + 64] = c_state[l + 64]; }
    __syncthreads();
    if (l < 64) {
        float a = sel_b1[l];
        for (int k = 0; k < 128; ++k) a += cs[k] * sel_w1[k * 64 + l];
        h1s[l] = gelu_exact(a);
    }
    if (l < 32) {
        float a = st_b1[l];
        for (int k = 0; k < 128; ++k) a += cs[k] * st_w1[k * 32 + l];
        h2s[l] = gelu_exact(a);
        float a2 = res_b1[l];
        for (int k = 0; k < 128; ++k) a2 += cs[k] * res_w1[k * 32 + l];
        h3s[l] = gelu_exact(a2);
    }
    __syncthreads();
    if (l < 4) {
        float a = sel_b2[l];
        for (int j = 0; j < 64; ++j) a += h1s[j] * sel_w2[j * 4 + l];
        lg[l] = a;
    }
    if (l >= 8 && l < 15) {
        int s = l - 8;
        float a = st_b2[s];
        for (int j = 0; j < 32; ++j) a += h2s[j] * st_w2[j * 7 + s];
        lg[4 + s] = a;
    }
    if (l == 32) {
        float a = res_b2[0];
        for (int j = 0; j < 32; ++j) a += h3s[j] * res_w2[j];
        lg[11] = a;
    }
    __syncthreads();
    if (l == 0) {
        float m = fmaxf(fmaxf(lg[0], lg[1]), fmaxf(lg[2], lg[3]));
        float e0 = expf(lg[0] - m), e1 = expf(lg[1] - m);
        float e2 = expf(lg[2] - m), e3 = expf(lg[3] - m);
        float s = e0 + e1 + e2 + e3;
        ctrl[0] = e0 / s; ctrl[1] = e1 / s; ctrl[2] = e2 / s; ctrl[3] = e3 / s;
        float m2 = lg[4];
        for (int i = 1; i < 7; ++i) m2 = fmaxf(m2, lg[4 + i]);
        float ss = 0.f, es[7];
        for (int i = 0; i < 7; ++i) { es[i] = expf(lg[4 + i] - m2); ss += es[i]; }
        float nsoft = 0.f;
        for (int i = 0; i < 7; ++i) nsoft += (es[i] / ss) * (float)(i + 2);
        int n = (int)(nsoft + 0.5f);
        n = n < 2 ? 2 : (n > 8 ? 8 : n);
        float alpha = 0.1f + 0.8f / (1.0f + expf(-lg[11]));
        ctrl[4] = alpha;
        ctrl[5] = (float)n;
    }
}

// ---------------------------------------------------------------------------
// Evolve kernel R16: 64-token tile, 512 threads = 8 waves.
// Wave w: rule r = w>>1, token-half th = w&1 (R15 compute structure).
// NEW: flat contiguous epilogue — f32x4 index idx = wave*128 + j*64 + lane,
// so each wave-instruction stores a contiguous 1 KB (full 128B lines; fixes
// R15's 32B-stride partial-sector RMW: WRITE 229MB -> ~payload). A token's
// 16 pieces sit in 16 consecutive lanes -> LN = shfl_xor{1,2,4,8} reduce.
// ---------------------------------------------------------------------------
__global__ __launch_bounds__(512, 4) void evolve_kernel(
    const float* __restrict__ cells, float* __restrict__ bufA,
    float* __restrict__ out, const float* __restrict__ ctrl,
    const _Float16* __restrict__ w1b, const _Float16* __restrict__ w2b,
    const float* __restrict__ b1, const float* __restrict__ b2,
    const float* __restrict__ ln_g, const float* __restrict__ ln_b, int iter)
{
    int n = (int)ctrl[5];
    if (iter >= n) return;
    const bool last = (iter == n - 1);

    const float* src = (iter == 0) ? cells
                       : ((((n - 1 - iter) & 1) == 0) ? (const float*)bufA
                                                      : (const float*)out);
    float* dst = (((n - 2 - iter) & 1) == 0) ? bufA : out;  // unused if last

    float alpha = ctrl[4];
    float beta = 1.0f - alpha;

    __shared__ _Float16 cellsL[66 * 72];                     // 9504 B
    __shared__ __align__(16) _Float16 arena[4][64 * 136];    // 4 x 17408 B

    int tile = blockIdx.x;
    int b = tile >> 7;
    int t0 = (tile & 127) << 6;
    const float* srcb = src + (size_t)b * TT * D;

    int tid = threadIdx.x;
    // stage cells tile (fp32 -> f16 LDS, RNE casts); 512 threads
    for (int idx = tid; idx < 66 * 16; idx += 512) {
        int row = idx >> 4;
        int c4 = (idx & 15) << 2;
        int tok = (t0 - 1 + row) & (TT - 1);
        f32x4 v = *(const f32x4*)(srcb + (size_t)tok * D + c4);
        *(f16x4*)&cellsL[row * 72 + c4] = cvt4_rne(v[0], v[1], v[2], v[3]);
    }
    __syncthreads();   // barrier 1

    int wave = tid >> 6;       // 0..7
    int lane = tid & 63;
    int lrow = lane & 15;
    int lgrp = lane >> 4;
    int r  = wave >> 1;        // rule
    int th = wave & 1;         // token half (32 tokens)
    float rwr = ctrl[r];

    const f16x8* w1v = (const f16x8*)w1b;
    const f16x8* w2v = (const f16x8*)w2b;
    _Float16* hb = &arena[r][0];

    // ---- GEMM1: h^T = W1_r^T X^T  (128 hcols x this wave's 32 tokens)
    f32x4 acc1[8][2];
#pragma unroll
    for (int ht = 0; ht < 8; ++ht)
#pragma unroll
        for (int nt = 0; nt < 2; ++nt)
            acc1[ht][nt] = (f32x4){0.f, 0.f, 0.f, 0.f};

#pragma unroll
    for (int ks = 0; ks < 6; ++ks) {
        int k0 = ks * 32 + lgrp * 8;
        int seg = k0 >> 6;                     // 0:c[t] 1:c[t-1] 2:c[t+1]
        int kk = k0 & 63;
        int drow = (seg == 0) ? 1 : ((seg == 1) ? 0 : 2);
        f16x8 a_[2];
#pragma unroll
        for (int nt = 0; nt < 2; ++nt)
            a_[nt] = *(const f16x8*)
                &cellsL[(th * 32 + nt * 16 + lrow + drow) * 72 + kk];
#pragma unroll
        for (int ht = 0; ht < 8; ++ht) {
            f16x8 wf = w1v[(ks * 32 + r * 8 + ht) * 64 + lane];
#pragma unroll
            for (int nt = 0; nt < 2; ++nt)
                acc1[ht][nt] = __builtin_amdgcn_mfma_f32_16x16x32_f16(wf, a_[nt], acc1[ht][nt], 0, 0, 0);
        }
    }

    // gelu + H store (wave-private rows: th*32 .. th*32+32)
#pragma unroll
    for (int ht = 0; ht < 8; ++ht) {
        f32x4 b1v = *(const f32x4*)&b1[r * HD + ht * 16 + lgrp * 4];
#pragma unroll
        for (int nt = 0; nt < 2; ++nt) {
            float g0 = gelu_tanh(acc1[ht][nt][0] + b1v[0]);
            float g1 = gelu_tanh(acc1[ht][nt][1] + b1v[1]);
            float g2 = gelu_tanh(acc1[ht][nt][2] + b1v[2]);
            float g3 = gelu_tanh(acc1[ht][nt][3] + b1v[3]);
            *(f16x4*)&hb[(th * 32 + nt * 16 + lrow) * 136 + ht * 16 + lgrp * 4]
                = cvt4_rne(g0, g1, g2, g3);
        }
    }

    // ---- GEMM2: out^T = W2_r^T H^T (64 d x own 32 tokens), wave-private
    f32x4 acc2[4][2];
#pragma unroll
    for (int mt = 0; mt < 4; ++mt)
#pragma unroll
        for (int nt = 0; nt < 2; ++nt)
            acc2[mt][nt] = (f32x4){0.f, 0.f, 0.f, 0.f};

#pragma unroll
    for (int ks2 = 0; ks2 < 4; ++ks2) {
        f16x8 a2[2];
#pragma unroll
        for (int nt = 0; nt < 2; ++nt)
            a2[nt] = *(const f16x8*)
                &hb[(th * 32 + nt * 16 + lrow) * 136 + ks2 * 32 + lgrp * 8];
#pragma unroll
        for (int mt = 0; mt < 4; ++mt) {
            f16x8 bw = w2v[((r * 4 + ks2) * 4 + mt) * 64 + lane];
#pragma unroll
            for (int nt = 0; nt < 2; ++nt)
                acc2[mt][nt] = __builtin_amdgcn_mfma_f32_16x16x32_f16(bw, a2[nt], acc2[mt][nt], 0, 0, 0);
        }
    }

    // tanh * rule_weight -> f32 mix slice over OWN half (H dead for this
    // wave after its GEMM2 reads; partner wave touches only its own half)
    float* mixw = (float*)hb;   // [64 tokens][stride 68 f32]
#pragma unroll
    for (int mt = 0; mt < 4; ++mt) {
        f32x4 b2v = *(const f32x4*)&b2[r * D + mt * 16 + lgrp * 4];
#pragma unroll
        for (int nt = 0; nt < 2; ++nt) {
            f32x4 o;
#pragma unroll
            for (int q = 0; q < 4; ++q)
                o[q] = rwr * fast_tanh(acc2[mt][nt][q] + b2v[q]);
            *(f32x4*)&mixw[(th * 32 + nt * 16 + lrow) * 68 + mt * 16 + lgrp * 4] = o;
        }
    }

    __syncthreads();   // barrier 2

    // ---- cross-rule reduce + alpha mix; FLAT contiguous mapping.
    // f32x4 index idx = wave*128 + j*64 + lane  (j=0,1): per wave-instr the
    // 64 lanes store tilebase + idx*16B contiguously (full lines, no RMW).
    // tok = idx>>4, p = idx&15; token's 16 pieces = 16 consecutive lanes.
    const float* ar0 = (const float*)&arena[0][0];
    const float* ar1 = (const float*)&arena[1][0];
    const float* ar2 = (const float*)&arena[2][0];
    const float* ar3 = (const float*)&arena[3][0];
#pragma unroll
    for (int j = 0; j < 2; ++j) {
        int idx = wave * 128 + j * 64 + lane;
        int tok = idx >> 4;
        int p   = idx & 15;
        int mbase = tok * 68 + p * 4;
        size_t roff = (size_t)b * TT * D + (size_t)(t0 + tok) * D + p * 4;

        f32x4 v0 = *(const f32x4*)(ar0 + mbase);
        f32x4 v1 = *(const f32x4*)(ar1 + mbase);
        f32x4 v2 = *(const f32x4*)(ar2 + mbase);
        f32x4 v3 = *(const f32x4*)(ar3 + mbase);
        f32x4 s  = *(const f32x4*)(src + roff);
        f32x4 ov;
        float m0 = 0.f, m1 = 0.f;
#pragma unroll
        for (int q = 0; q < 4; ++q) {
            float v = alpha * s[q] + beta * (v0[q] + v1[q] + v2[q] + v3[q]);
            ov[q] = v; m0 += v; m1 += v * v;
        }

        if (!last) {
            *(f32x4*)(dst + roff) = ov;
        } else {
            // fused LN: reduce across the 16-lane group holding this token
            m0 += __shfl_xor(m0, 1, 64); m1 += __shfl_xor(m1, 1, 64);
            m0 += __shfl_xor(m0, 2, 64); m1 += __shfl_xor(m1, 2, 64);
            m0 += __shfl_xor(m0, 4, 64); m1 += __shfl_xor(m1, 4, 64);
            m0 += __shfl_xor(m0, 8, 64); m1 += __shfl_xor(m1, 8, 64);
            float mu = m0 * (1.0f / 64.0f);
            float inv = rsqrtf(m1 * (1.0f / 64.0f) - mu * mu + 1e-5f);
            f32x4 g4 = *(const f32x4*)&ln_g[p * 4];
            f32x4 b4 = *(const f32x4*)&ln_b[p * 4];
            f32x4 o;
#pragma unroll
            for (int q = 0; q < 4; ++q)
                o[q] = (ov[q] - mu) * inv * g4[q] + b4[q];
            *(f32x4*)(out + roff) = o;
        }
    }
}

// ---------------------------------------------------------------------------
extern "C" void kernel_launch(void* const* d_in, const int* in_sizes, int n_in,
                              void* d_out, int out_size, void* d_ws, size_t ws_size,
                              hipStream_t stream) {
    const float* cells   = (const float*)d_in[0];
    const float* c_state = (const float*)d_in[1];
    const float* rule_w1 = (const float*)d_in[2];
    const float* rule_b1 = (const float*)d_in[3];
    const float* rule_w2 = (const float*)d_in[4];
    const float* rule_b2 = (const float*)d_in[5];
    const float* sel_w1  = (const float*)d_in[6];
    const float* sel_b1  = (const float*)d_in[7];
    const float* sel_w2  = (const float*)d_in[8];
    const float* sel_b2  = (const float*)d_in[9];
    const float* st_w1   = (const float*)d_in[10];
    const float* st_b1   = (const float*)d_in[11];
    const float* st_w2   = (const float*)d_in[12];
    const float* st_b2   = (const float*)d_in[13];
    const float* res_w1  = (const float*)d_in[14];
    const float* res_b1  = (const float*)d_in[15];
    const float* res_w2  = (const float*)d_in[16];
    const float* res_b2  = (const float*)d_in[17];
    const float* ln_g    = (const float*)d_in[18];
    const float* ln_b    = (const float*)d_in[19];

    float* out = (float*)d_out;
    char* ws = (char*)d_ws;
    float* ctrl = (float*)ws;                              // 64 B
    _Float16* w1b = (_Float16*)(ws + 256);                 // 196608 B
    _Float16* w2b = (_Float16*)(ws + 256 + 196608);        // 65536 B
    float* bufA = (float*)(ws + (512u * 1024u));           // 64 MiB ping buffer

    prep_control_kernel<<<65, 256, 0, stream>>>(
        rule_w1, rule_w2, w1b, w2b, c_state,
        sel_w1, sel_b1, sel_w2, sel_b2,
        st_w1, st_b1, st_w2, st_b2,
        res_w1, res_b1, res_w2, res_b2, ctrl);

    // 8 potential iterations; dead ones early-exit on device. Buffers are
    // selected on-device (backwards parity); last live iteration applies
    // fused LayerNorm and writes d_out.
    for (int i = 0; i < 8; ++i) {
        evolve_kernel<<<4096, 512, 0, stream>>>(cells, bufA, out, ctrl,
                                                w1b, w2b, rule_b1, rule_b2,
                                                ln_g, ln_b, i);
    }
}

// Round 17
// 553.310 us; speedup vs baseline: 1.3982x; 1.0973x over previous
//
#include <hip/hip_runtime.h>
#include <cmath>

#define D 64
#define HD 128
#define K1 192
#define TT 8192
#define BBATCH 32
#define RULES 4

typedef _Float16 f16x8 __attribute__((ext_vector_type(8)));
typedef _Float16 f16x4 __attribute__((ext_vector_type(4)));
typedef float f32x4 __attribute__((ext_vector_type(4)));

__device__ __forceinline__ float gelu_exact(float x) {
    return 0.5f * x * (1.0f + erff(x * 0.70710678118654752f));
}

__device__ __forceinline__ float fast_rcp(float x) { return __builtin_amdgcn_rcpf(x); }
__device__ __forceinline__ float fast_exp2(float x) { return __builtin_amdgcn_exp2f(x); }

// tanh-approx GELU (R8, passing): ~6 VALU + 2 trans.
__device__ __forceinline__ float gelu_tanh(float x) {
    float x2 = x * x;
    float t = x * fmaf(x2, -0.10294443f, -2.30220820f);
    return x * fast_rcp(1.0f + fast_exp2(t));
}
// tanh(x) = 1 - 2/(exp2(2*log2e*x)+1) ; exact identity, saturates cleanly
__device__ __forceinline__ float fast_tanh(float x) {
    float e = fast_exp2(x * 2.8853900817779268f);
    return 1.0f - 2.0f * fast_rcp(e + 1.0f);
}

__device__ __forceinline__ f16x4 cvt4_rne(float a, float b, float c, float d) {
    f16x4 r;
    r[0] = (_Float16)a; r[1] = (_Float16)b;
    r[2] = (_Float16)c; r[3] = (_Float16)d;
    return r;
}

// ---------------------------------------------------------------------------
// Prep+control kernel (unchanged from R14 — verified):
//   blocks 0..63: weight re-layout; block 64: control -> ctrl[0..5].
// ---------------------------------------------------------------------------
__global__ __launch_bounds__(256) void prep_control_kernel(
    const float* __restrict__ rule_w1, const float* __restrict__ rule_w2,
    _Float16* __restrict__ w1b, _Float16* __restrict__ w2b,
    const float* __restrict__ c_state,
    const float* __restrict__ sel_w1, const float* __restrict__ sel_b1,
    const float* __restrict__ sel_w2, const float* __restrict__ sel_b2,
    const float* __restrict__ st_w1,  const float* __restrict__ st_b1,
    const float* __restrict__ st_w2,  const float* __restrict__ st_b2,
    const float* __restrict__ res_w1, const float* __restrict__ res_b1,
    const float* __restrict__ res_w2, const float* __restrict__ res_b2,
    float* __restrict__ ctrl)
{
    if (blockIdx.x < 64) {
        int t = blockIdx.x * 256 + threadIdx.x;
        if (t < 12288) {
            int lane = t & 63;
            int x = t >> 6;          // 0..191
            int htile = x & 31;      // global h tile (r = htile>>3)
            int ks = x >> 5;         // 0..5
            int r = htile >> 3;
            int h128 = (htile & 7) * 16 + (lane & 15);
            int kbase = ks * 32 + (lane >> 4) * 8;
            f16x8 v;
#pragma unroll
            for (int j = 0; j < 8; ++j)
                v[j] = (_Float16)rule_w1[((size_t)r * K1 + kbase + j) * HD + h128];
            ((f16x8*)w1b)[(ks * 32 + htile) * 64 + lane] = v;
        } else if (t < 12288 + 4096) {
            int u = t - 12288;
            int lane = u & 63;
            int mt = (u >> 6) & 3;   // d tile
            int ks2 = (u >> 8) & 3;  // hidden-k tile
            int r = u >> 10;
            int kbase = ks2 * 32 + (lane >> 4) * 8;
            int d = mt * 16 + (lane & 15);
            f16x8 v;
#pragma unroll
            for (int j = 0; j < 8; ++j)
                v[j] = (_Float16)rule_w2[((size_t)r * HD + kbase + j) * D + d];
            ((f16x8*)w2b)[((r * 4 + ks2) * 4 + mt) * 64 + lane] = v;
        }
        return;
    }

    // ---- control block (blockIdx.x == 64)
    __shared__ float cs[128];
    __shared__ float h1s[64], h2s[32], h3s[32];
    __shared__ float lg[12];
    int l = threadIdx.x;
    if (l < 64) { cs[l] = c_state[l]; cs[l + 64] = c_state[l + 64]; }
    __syncthreads();
    if (l < 64) {
        float a = sel_b1[l];
        for (int k = 0; k < 128; ++k) a += cs[k] * sel_w1[k * 64 + l];
        h1s[l] = gelu_exact(a);
    }
    if (l < 32) {
        float a = st_b1[l];
        for (int k = 0; k < 128; ++k) a += cs[k] * st_w1[k * 32 + l];
        h2s[l] = gelu_exact(a);
        float a2 = res_b1[l];
        for (int k = 0; k < 128; ++k) a2 += cs[k] * res_w1[k * 32 + l];
        h3s[l] = gelu_exact(a2);
    }
    __syncthreads();
    if (l < 4) {
        float a = sel_b2[l];
        for (int j = 0; j < 64; ++j) a += h1s[j] * sel_w2[j * 4 + l];
        lg[l] = a;
    }
    if (l >= 8 && l < 15) {
        int s = l - 8;
        float a = st_b2[s];
        for (int j = 0; j < 32; ++j) a += h2s[j] * st_w2[j * 7 + s];
        lg[4 + s] = a;
    }
    if (l == 32) {
        float a = res_b2[0];
        for (int j = 0; j < 32; ++j) a += h3s[j] * res_w2[j];
        lg[11] = a;
    }
    __syncthreads();
    if (l == 0) {
        float m = fmaxf(fmaxf(lg[0], lg[1]), fmaxf(lg[2], lg[3]));
        float e0 = expf(lg[0] - m), e1 = expf(lg[1] - m);
        float e2 = expf(lg[2] - m), e3 = expf(lg[3] - m);
        float s = e0 + e1 + e2 + e3;
        ctrl[0] = e0 / s; ctrl[1] = e1 / s; ctrl[2] = e2 / s; ctrl[3] = e3 / s;
        float m2 = lg[4];
        for (int i = 1; i < 7; ++i) m2 = fmaxf(m2, lg[4 + i]);
        float ss = 0.f, es[7];
        for (int i = 0; i < 7; ++i) { es[i] = expf(lg[4 + i] - m2); ss += es[i]; }
        float nsoft = 0.f;
        for (int i = 0; i < 7; ++i) nsoft += (es[i] / ss) * (float)(i + 2);
        int n = (int)(nsoft + 0.5f);
        n = n < 2 ? 2 : (n > 8 ? 8 : n);
        float alpha = 0.1f + 0.8f / (1.0f + expf(-lg[11]));
        ctrl[4] = alpha;
        ctrl[5] = (float)n;
    }
}

// ---------------------------------------------------------------------------
// Evolve kernel R17: R16 compute structure (64-token tile, 8 waves,
// rule x token-half partition) with F16 inter-iteration state:
//  - ping-pong buffers fb0/fb1 are f16 (iter i: src = i==0 ? cells(f32)
//    : fb[(i+1)&1], dst = fb[i&1]; last iter writes LN'd f32 to out —
//    never aliases its source).
//  - steady-state staging is a pure f16->LDS 16B copy (no cvt).
//  - epilogue alpha-mix reads src from cellsL (LDS f16) instead of global.
// Numeric delta: alpha*(f16-rounded cells) per iter, ~+2e-3 absmax total.
// ---------------------------------------------------------------------------
__global__ __launch_bounds__(512, 4) void evolve_kernel(
    const float* __restrict__ cells, _Float16* __restrict__ fb0,
    _Float16* __restrict__ fb1, float* __restrict__ out,
    const float* __restrict__ ctrl,
    const _Float16* __restrict__ w1b, const _Float16* __restrict__ w2b,
    const float* __restrict__ b1, const float* __restrict__ b2,
    const float* __restrict__ ln_g, const float* __restrict__ ln_b, int iter)
{
    int n = (int)ctrl[5];
    if (iter >= n) return;
    const bool last = (iter == n - 1);

    const _Float16* s16 = (iter & 1) ? fb0 : fb1;   // valid for iter >= 1
    _Float16*       d16 = (iter & 1) ? fb1 : fb0;   // unused if last

    float alpha = ctrl[4];
    float beta = 1.0f - alpha;

    __shared__ _Float16 cellsL[66 * 72];                     // 9504 B
    __shared__ __align__(16) _Float16 arena[4][64 * 136];    // 4 x 17408 B

    int tile = blockIdx.x;
    int b = tile >> 7;
    int t0 = (tile & 127) << 6;

    int tid = threadIdx.x;
    // ---- stage cells tile into LDS f16
    if (iter == 0) {
        const float* srcb = cells + (size_t)b * TT * D;
        for (int idx = tid; idx < 66 * 16; idx += 512) {
            int row = idx >> 4;
            int c4 = (idx & 15) << 2;
            int tok = (t0 - 1 + row) & (TT - 1);
            f32x4 v = *(const f32x4*)(srcb + (size_t)tok * D + c4);
            *(f16x4*)&cellsL[row * 72 + c4] = cvt4_rne(v[0], v[1], v[2], v[3]);
        }
    } else {
        const _Float16* sb = s16 + (size_t)b * TT * D;
        for (int idx = tid; idx < 66 * 8; idx += 512) {
            int row = idx >> 3;
            int c8 = (idx & 7) << 3;
            int tok = (t0 - 1 + row) & (TT - 1);
            *(f16x8*)&cellsL[row * 72 + c8] =
                *(const f16x8*)(sb + (size_t)tok * D + c8);
        }
    }
    __syncthreads();   // barrier 1

    int wave = tid >> 6;       // 0..7
    int lane = tid & 63;
    int lrow = lane & 15;
    int lgrp = lane >> 4;
    int r  = wave >> 1;        // rule
    int th = wave & 1;         // token half (32 tokens)
    float rwr = ctrl[r];

    const f16x8* w1v = (const f16x8*)w1b;
    const f16x8* w2v = (const f16x8*)w2b;
    _Float16* hb = &arena[r][0];

    // ---- GEMM1: h^T = W1_r^T X^T  (128 hcols x this wave's 32 tokens)
    f32x4 acc1[8][2];
#pragma unroll
    for (int ht = 0; ht < 8; ++ht)
#pragma unroll
        for (int nt = 0; nt < 2; ++nt)
            acc1[ht][nt] = (f32x4){0.f, 0.f, 0.f, 0.f};

#pragma unroll
    for (int ks = 0; ks < 6; ++ks) {
        int k0 = ks * 32 + lgrp * 8;
        int seg = k0 >> 6;                     // 0:c[t] 1:c[t-1] 2:c[t+1]
        int kk = k0 & 63;
        int drow = (seg == 0) ? 1 : ((seg == 1) ? 0 : 2);
        f16x8 a_[2];
#pragma unroll
        for (int nt = 0; nt < 2; ++nt)
            a_[nt] = *(const f16x8*)
                &cellsL[(th * 32 + nt * 16 + lrow + drow) * 72 + kk];
#pragma unroll
        for (int ht = 0; ht < 8; ++ht) {
            f16x8 wf = w1v[(ks * 32 + r * 8 + ht) * 64 + lane];
#pragma unroll
            for (int nt = 0; nt < 2; ++nt)
                acc1[ht][nt] = __builtin_amdgcn_mfma_f32_16x16x32_f16(wf, a_[nt], acc1[ht][nt], 0, 0, 0);
        }
    }

    // gelu + H store (wave-private rows: th*32 .. th*32+32)
#pragma unroll
    for (int ht = 0; ht < 8; ++ht) {
        f32x4 b1v = *(const f32x4*)&b1[r * HD + ht * 16 + lgrp * 4];
#pragma unroll
        for (int nt = 0; nt < 2; ++nt) {
            float g0 = gelu_tanh(acc1[ht][nt][0] + b1v[0]);
            float g1 = gelu_tanh(acc1[ht][nt][1] + b1v[1]);
            float g2 = gelu_tanh(acc1[ht][nt][2] + b1v[2]);
            float g3 = gelu_tanh(acc1[ht][nt][3] + b1v[3]);
            *(f16x4*)&hb[(th * 32 + nt * 16 + lrow) * 136 + ht * 16 + lgrp * 4]
                = cvt4_rne(g0, g1, g2, g3);
        }
    }

    // ---- GEMM2: out^T = W2_r^T H^T (64 d x own 32 tokens), wave-private
    f32x4 acc2[4][2];
#pragma unroll
    for (int mt = 0; mt < 4; ++mt)
#pragma unroll
        for (int nt = 0; nt < 2; ++nt)
            acc2[mt][nt] = (f32x4){0.f, 0.f, 0.f, 0.f};

#pragma unroll
    for (int ks2 = 0; ks2 < 4; ++ks2) {
        f16x8 a2[2];
#pragma unroll
        for (int nt = 0; nt < 2; ++nt)
            a2[nt] = *(const f16x8*)
                &hb[(th * 32 + nt * 16 + lrow) * 136 + ks2 * 32 + lgrp * 8];
#pragma unroll
        for (int mt = 0; mt < 4; ++mt) {
            f16x8 bw = w2v[((r * 4 + ks2) * 4 + mt) * 64 + lane];
#pragma unroll
            for (int nt = 0; nt < 2; ++nt)
                acc2[mt][nt] = __builtin_amdgcn_mfma_f32_16x16x32_f16(bw, a2[nt], acc2[mt][nt], 0, 0, 0);
        }
    }

    // tanh * rule_weight -> f32 mix slice over OWN half (H dead for this
    // wave after its GEMM2 reads; partner wave touches only its own half)
    float* mixw = (float*)hb;   // [64 tokens][stride 68 f32]
#pragma unroll
    for (int mt = 0; mt < 4; ++mt) {
        f32x4 b2v = *(const f32x4*)&b2[r * D + mt * 16 + lgrp * 4];
#pragma unroll
        for (int nt = 0; nt < 2; ++nt) {
            f32x4 o;
#pragma unroll
            for (int q = 0; q < 4; ++q)
                o[q] = rwr * fast_tanh(acc2[mt][nt][q] + b2v[q]);
            *(f32x4*)&mixw[(th * 32 + nt * 16 + lrow) * 68 + mt * 16 + lgrp * 4] = o;
        }
    }

    __syncthreads();   // barrier 2

    // ---- cross-rule reduce + alpha mix; FLAT contiguous mapping.
    // f32x4 index idx = wave*128 + j*64 + lane: tok = idx>>4, p = idx&15.
    // src comes from cellsL (token tok -> LDS row tok+1) — no global read.
    // dst: f16x4 (8B) per lane-instr, lane-contiguous 512B per wave-instr.
    const float* ar0 = (const float*)&arena[0][0];
    const float* ar1 = (const float*)&arena[1][0];
    const float* ar2 = (const float*)&arena[2][0];
    const float* ar3 = (const float*)&arena[3][0];
#pragma unroll
    for (int j = 0; j < 2; ++j) {
        int idx = wave * 128 + j * 64 + lane;
        int tok = idx >> 4;
        int p   = idx & 15;
        int mbase = tok * 68 + p * 4;
        size_t roff = (size_t)b * TT * D + (size_t)(t0 + tok) * D + p * 4;

        f32x4 v0 = *(const f32x4*)(ar0 + mbase);
        f32x4 v1 = *(const f32x4*)(ar1 + mbase);
        f32x4 v2 = *(const f32x4*)(ar2 + mbase);
        f32x4 v3 = *(const f32x4*)(ar3 + mbase);
        f16x4 sh = *(const f16x4*)&cellsL[(tok + 1) * 72 + p * 4];
        f32x4 ov;
        float m0 = 0.f, m1 = 0.f;
#pragma unroll
        for (int q = 0; q < 4; ++q) {
            float v = alpha * (float)sh[q]
                    + beta * (v0[q] + v1[q] + v2[q] + v3[q]);
            ov[q] = v; m0 += v; m1 += v * v;
        }

        if (!last) {
            *(f16x4*)(d16 + roff) = cvt4_rne(ov[0], ov[1], ov[2], ov[3]);
        } else {
            // fused LN: reduce across the 16-lane group holding this token
            m0 += __shfl_xor(m0, 1, 64); m1 += __shfl_xor(m1, 1, 64);
            m0 += __shfl_xor(m0, 2, 64); m1 += __shfl_xor(m1, 2, 64);
            m0 += __shfl_xor(m0, 4, 64); m1 += __shfl_xor(m1, 4, 64);
            m0 += __shfl_xor(m0, 8, 64); m1 += __shfl_xor(m1, 8, 64);
            float mu = m0 * (1.0f / 64.0f);
            float inv = rsqrtf(m1 * (1.0f / 64.0f) - mu * mu + 1e-5f);
            f32x4 g4 = *(const f32x4*)&ln_g[p * 4];
            f32x4 b4 = *(const f32x4*)&ln_b[p * 4];
            f32x4 o;
#pragma unroll
            for (int q = 0; q < 4; ++q)
                o[q] = (ov[q] - mu) * inv * g4[q] + b4[q];
            *(f32x4*)(out + roff) = o;
        }
    }
}

// ---------------------------------------------------------------------------
extern "C" void kernel_launch(void* const* d_in, const int* in_sizes, int n_in,
                              void* d_out, int out_size, void* d_ws, size_t ws_size,
                              hipStream_t stream) {
    const float* cells   = (const float*)d_in[0];
    const float* c_state = (const float*)d_in[1];
    const float* rule_w1 = (const float*)d_in[2];
    const float* rule_b1 = (const float*)d_in[3];
    const float* rule_w2 = (const float*)d_in[4];
    const float* rule_b2 = (const float*)d_in[5];
    const float* sel_w1  = (const float*)d_in[6];
    const float* sel_b1  = (const float*)d_in[7];
    const float* sel_w2  = (const float*)d_in[8];
    const float* sel_b2  = (const float*)d_in[9];
    const float* st_w1   = (const float*)d_in[10];
    const float* st_b1   = (const float*)d_in[11];
    const float* st_w2   = (const float*)d_in[12];
    const float* st_b2   = (const float*)d_in[13];
    const float* res_w1  = (const float*)d_in[14];
    const float* res_b1  = (const float*)d_in[15];
    const float* res_w2  = (const float*)d_in[16];
    const float* res_b2  = (const float*)d_in[17];
    const float* ln_g    = (const float*)d_in[18];
    const float* ln_b    = (const float*)d_in[19];

    float* out = (float*)d_out;
    char* ws = (char*)d_ws;
    float* ctrl = (float*)ws;                              // 64 B
    _Float16* w1b = (_Float16*)(ws + 256);                 // 196608 B
    _Float16* w2b = (_Float16*)(ws + 256 + 196608);        // 65536 B
    // two f16 ping-pong state buffers (32 MB each)
    _Float16* fb0 = (_Float16*)(ws + (512u * 1024u));
    _Float16* fb1 = (_Float16*)(ws + (512u * 1024u) + 33554432u);

    prep_control_kernel<<<65, 256, 0, stream>>>(
        rule_w1, rule_w2, w1b, w2b, c_state,
        sel_w1, sel_b1, sel_w2, sel_b2,
        st_w1, st_b1, st_w2, st_b2,
        res_w1, res_b1, res_w2, res_b2, ctrl);

    // 8 potential iterations; dead ones early-exit on device. f16 ping-pong
    // between fb0/fb1; last live iteration applies fused LayerNorm -> d_out.
    for (int i = 0; i < 8; ++i) {
        evolve_kernel<<<4096, 512, 0, stream>>>(cells, fb0, fb1, out, ctrl,
                                                w1b, w2b, rule_b1, rule_b2,
                                                ln_g, ln_b, i);
    }
}